// Round 1
// baseline (1795.550 us; speedup 1.0000x reference)
//
#include <hip/hip_runtime.h>
#include <hip/hip_bf16.h>

// Problem constants (from reference): N=10000, D_IN=128, F1=F2=20, D_OUT=128
constexpr int NN   = 10000;
constexpr int DIN  = 128;
constexpr int F    = 20;       // F1 == F2 == 20
constexpr int DOUT = 128;

// adjmm tiling
constexpr int TM     = 256;    // rows per block (1 row per thread)
constexpr int TKA    = 40;     // K per LDS tile
constexpr int KSPLIT = 25;     // K ranges: 10000/25 = 400 per block
constexpr int KRANGE = NN / KSPLIT;          // 400
constexpr int NTILES = KRANGE / TKA;         // 10
constexpr int ROWBLK = (NN + TM - 1) / TM;   // 40

// ---------------------------------------------------------------------------
// out[i,f] = sum_k x[i,k] * W[k,f]   (K=128, F=20)  -> t1
// ---------------------------------------------------------------------------
__global__ __launch_bounds__(256) void gemm_x_w1(const float* __restrict__ x,
                                                 const float* __restrict__ W,
                                                 float* __restrict__ out) {
    int t = blockIdx.x * 256 + threadIdx.x;
    if (t >= NN * F) return;
    int i = t / F, f = t % F;
    const float4* xp = (const float4*)(x + (size_t)i * DIN);
    float s = 0.f;
#pragma unroll
    for (int k4 = 0; k4 < DIN / 4; ++k4) {
        float4 xv = xp[k4];
        int k = k4 * 4;
        s += xv.x * W[(k + 0) * F + f];
        s += xv.y * W[(k + 1) * F + f];
        s += xv.z * W[(k + 2) * F + f];
        s += xv.w * W[(k + 3) * F + f];
    }
    out[t] = s;
}

// ---------------------------------------------------------------------------
// out[i,g] = sum_f in[i,f] * W[f,g]   (K=20, F=20)
// ---------------------------------------------------------------------------
__global__ __launch_bounds__(256) void gemm_h_w2(const float* __restrict__ h,
                                                 const float* __restrict__ W,
                                                 float* __restrict__ out) {
    int t = blockIdx.x * 256 + threadIdx.x;
    if (t >= NN * F) return;
    int i = t / F, g = t % F;
    const float* hp = h + (size_t)i * F;
    float s = 0.f;
#pragma unroll
    for (int f = 0; f < F; ++f) s += hp[f] * W[f * F + g];
    out[t] = s;
}

// ---------------------------------------------------------------------------
// out[t] = relu(in[t] + b[t % F])
// ---------------------------------------------------------------------------
__global__ __launch_bounds__(256) void bias_relu(const float* __restrict__ in,
                                                 const float* __restrict__ b,
                                                 float* __restrict__ out) {
    int t = blockIdx.x * 256 + threadIdx.x;
    if (t >= NN * F) return;
    out[t] = fmaxf(in[t] + b[t % F], 0.f);
}

// ---------------------------------------------------------------------------
// out[i,:F] += adj[i, kr] @ t[kr, :F]   for this block's K-range kr.
// adj staged transposed in LDS (conflict-free b32 reads); t fragment read from
// global via block-uniform addresses (scalarizes to s_load; L2-resident).
// ---------------------------------------------------------------------------
__global__ __launch_bounds__(256) void adjmm(const float* __restrict__ adj,
                                             const float* __restrict__ t,
                                             float* __restrict__ out) {
    __shared__ float adj_sT[TKA][TM + 1];   // 40 x 257 x 4B = 41,120 B

    const int tid = threadIdx.x;
    const int row0 = blockIdx.x * TM;
    const int k_begin = blockIdx.y * KRANGE;
    const int row = row0 + tid;

    float4 acc[5];
#pragma unroll
    for (int c = 0; c < 5; ++c) acc[c] = make_float4(0.f, 0.f, 0.f, 0.f);

    for (int kt = 0; kt < NTILES; ++kt) {
        const int k0 = k_begin + kt * TKA;
        __syncthreads();   // protect previous tile's reads
        // stage adj[row0..row0+255][k0..k0+39], transposed. 2560 float4 loads.
#pragma unroll
        for (int it = 0; it < 10; ++it) {
            int idx = tid + it * 256;          // 0..2559
            int rr = idx / 10;                 // 10 float4 per row
            int c4 = idx % 10;
            int grow = row0 + rr;
            float4 v = make_float4(0.f, 0.f, 0.f, 0.f);
            if (grow < NN)
                v = *(const float4*)(adj + (size_t)grow * NN + k0 + c4 * 4);
            adj_sT[c4 * 4 + 0][rr] = v.x;
            adj_sT[c4 * 4 + 1][rr] = v.y;
            adj_sT[c4 * 4 + 2][rr] = v.z;
            adj_sT[c4 * 4 + 3][rr] = v.w;
        }
        __syncthreads();
        // compute: per 4 k's, 4 LDS b32 + 20 uniform float4 loads + 80 FMA
        for (int ks = 0; ks < TKA / 4; ++ks) {
            const int kk = ks * 4;
            float a[4];
#pragma unroll
            for (int j = 0; j < 4; ++j) a[j] = adj_sT[kk + j][tid];
#pragma unroll
            for (int j = 0; j < 4; ++j) {
                const float4* tp = (const float4*)(t + (size_t)(k0 + kk + j) * F);
#pragma unroll
                for (int c = 0; c < 5; ++c) {
                    float4 tv = tp[c];
                    acc[c].x += a[j] * tv.x;
                    acc[c].y += a[j] * tv.y;
                    acc[c].z += a[j] * tv.z;
                    acc[c].w += a[j] * tv.w;
                }
            }
        }
    }

    if (row < NN) {
        float* op = out + (size_t)row * F;
#pragma unroll
        for (int c = 0; c < 5; ++c) {
            atomicAdd(op + c * 4 + 0, acc[c].x);
            atomicAdd(op + c * 4 + 1, acc[c].y);
            atomicAdd(op + c * 4 + 2, acc[c].z);
            atomicAdd(op + c * 4 + 3, acc[c].w);
        }
    }
}

// ---------------------------------------------------------------------------
// out[i,f] = relu( relu( sum_g u[i,g]*W3[g,f] + b3[f] ) + x[i,f] )
// ---------------------------------------------------------------------------
__global__ __launch_bounds__(256) void final_fuse(const float* __restrict__ u,
                                                  const float* __restrict__ W3,
                                                  const float* __restrict__ b3,
                                                  const float* __restrict__ x,
                                                  float* __restrict__ out) {
    int t = blockIdx.x * 256 + threadIdx.x;
    if (t >= NN * DOUT) return;
    int i = t / DOUT, f = t % DOUT;
    const float* up = u + (size_t)i * F;
    float s = b3[f];
#pragma unroll
    for (int g = 0; g < F; ++g) s += up[g] * W3[g * DOUT + f];
    float h = fmaxf(s, 0.f);
    out[t] = fmaxf(h + x[t], 0.f);
}

// ---------------------------------------------------------------------------
extern "C" void kernel_launch(void* const* d_in, const int* in_sizes, int n_in,
                              void* d_out, int out_size, void* d_ws, size_t ws_size,
                              hipStream_t stream) {
    const float* x   = (const float*)d_in[0];
    const float* adj = (const float*)d_in[1];
    const float* W1  = (const float*)d_in[2];
    const float* b1  = (const float*)d_in[3];
    const float* W2  = (const float*)d_in[4];
    const float* b2  = (const float*)d_in[5];
    const float* W3  = (const float*)d_in[6];
    const float* b3  = (const float*)d_in[7];
    float* out = (float*)d_out;

    float* A = (float*)d_ws;            // N x F
    float* B = A + NN * F;              // N x F
    float* C = B + NN * F;              // N x F
    const size_t nf_bytes = (size_t)NN * F * sizeof(float);

    const int blk_nf = (NN * F + 255) / 256;        // 782
    const int blk_no = (NN * DOUT + 255) / 256;     // 5000
    dim3 adj_grid(ROWBLK, KSPLIT);                  // 40 x 25 = 1000 blocks

    // Layer 1: h1 = relu(adj @ (x@W1) + b1)
    gemm_x_w1<<<blk_nf, 256, 0, stream>>>(x, W1, A);
    hipMemsetAsync(B, 0, nf_bytes, stream);
    adjmm<<<adj_grid, 256, 0, stream>>>(adj, A, B);
    bias_relu<<<blk_nf, 256, 0, stream>>>(B, b1, C);

    // Layer 2: h2 = relu(adj @ (h1@W2) + b2)
    gemm_h_w2<<<blk_nf, 256, 0, stream>>>(C, W2, A);
    hipMemsetAsync(B, 0, nf_bytes, stream);
    adjmm<<<adj_grid, 256, 0, stream>>>(adj, A, B);
    bias_relu<<<blk_nf, 256, 0, stream>>>(B, b2, C);

    // Layer 3 (reassociated): u = adj @ h2 ; out = relu(relu(u@W3 + b3) + x)
    hipMemsetAsync(A, 0, nf_bytes, stream);
    adjmm<<<adj_grid, 256, 0, stream>>>(adj, C, A);
    final_fuse<<<blk_no, 256, 0, stream>>>(A, W3, b3, x, out);
}